// Round 1
// baseline (2443.186 us; speedup 1.0000x reference)
//
#include <hip/hip_runtime.h>
#include <hip/hip_bf16.h>

#define N_NODES   32000
#define N_EDGES   512000
#define IN_CH     128
#define HID       256
#define HEADS     8
#define D_HEAD    32
#define N_LAYERS  4
#define N_GRAPHS  64

// ---------------------------------------------------------------- CSR build
__global__ __launch_bounds__(256) void count_kernel(const int* __restrict__ ei,
                                                    int* __restrict__ deg) {
    int e = blockIdx.x * 256 + threadIdx.x;
    if (e < N_EDGES) atomicAdd(&deg[ei[N_EDGES + e]], 1);
}

__global__ __launch_bounds__(256) void scan_kernel(const int* __restrict__ deg,
                                                   int* __restrict__ indptr,
                                                   int* __restrict__ cursor) {
    __shared__ int wsum[4];
    __shared__ int carry_s;
    __shared__ int total_s;
    int tid = threadIdx.x;
    int lane = tid & 63, wave = tid >> 6;
    if (tid == 0) carry_s = 0;
    __syncthreads();
    for (int base = 0; base < N_NODES; base += 256) {
        int i = base + tid;
        int v = (i < N_NODES) ? deg[i] : 0;
        int x = v;
        #pragma unroll
        for (int off = 1; off < 64; off <<= 1) {
            int t = __shfl_up(x, off, 64);
            if (lane >= off) x += t;
        }
        if (lane == 63) wsum[wave] = x;
        __syncthreads();
        if (tid == 0) {
            int s = 0;
            #pragma unroll
            for (int w = 0; w < 4; ++w) { int t = wsum[w]; wsum[w] = s; s += t; }
            total_s = s;
        }
        __syncthreads();
        int excl = carry_s + wsum[wave] + x - v;
        if (i < N_NODES) { indptr[i] = excl; cursor[i] = excl; }
        __syncthreads();
        if (tid == 0) carry_s += total_s;
        __syncthreads();
    }
    if (tid == 0) indptr[N_NODES] = carry_s;
}

__global__ __launch_bounds__(256) void scatter_kernel(const int* __restrict__ ei,
                                                      int* __restrict__ cursor,
                                                      int* __restrict__ ssrc) {
    int e = blockIdx.x * 256 + threadIdx.x;
    if (e < N_EDGES) {
        int dst = ei[N_EDGES + e];
        int pos = atomicAdd(&cursor[dst], 1);
        ssrc[pos] = ei[e];
    }
}

// ---------------------------------------------------------------- pe MLP stage 1
__global__ __launch_bounds__(256) void pe1_kernel(const float* __restrict__ lpe,
                                                  const float* __restrict__ w1,
                                                  const float* __restrict__ b1,
                                                  float* __restrict__ t1) {
    __shared__ float l[16];
    int n = blockIdx.x, j = threadIdx.x;
    if (j < 16) l[j] = lpe[n * 16 + j];
    __syncthreads();
    float s = b1[j];
    #pragma unroll
    for (int kk = 0; kk < 16; ++kk) s += l[kk] * w1[j * 16 + kk];
    t1[(size_t)n * HID + j] = fmaxf(s, 0.0f);
}

// ---------------------------------------------------------------- generic f32 GEMM
// C[M x NOut] (+)= A[M x K] @ W[NOut x K]^T + bias.  BM=128 BN=64 BK=16, 256 thr.
template <bool ACC>
__global__ __launch_bounds__(256) void gemm_kernel(const float* __restrict__ A,
                                                   const float* __restrict__ W,
                                                   const float* __restrict__ bias,
                                                   float* __restrict__ C,
                                                   int K, int NOut) {
    __shared__ float As[128][17];
    __shared__ float Bs[64][17];
    int tid = threadIdx.x;
    int r0 = blockIdx.x * 128;
    int c0 = blockIdx.y * 64;
    int ty = tid >> 4, tx = tid & 15;
    int am = tid >> 1, ak = (tid & 1) * 8;
    int bm = tid >> 2, bk = (tid & 3) * 4;
    float acc[8][4] = {};
    for (int k0 = 0; k0 < K; k0 += 16) {
        float4 a0 = *(const float4*)&A[(size_t)(r0 + am) * K + k0 + ak];
        float4 a1 = *(const float4*)&A[(size_t)(r0 + am) * K + k0 + ak + 4];
        As[am][ak + 0] = a0.x; As[am][ak + 1] = a0.y; As[am][ak + 2] = a0.z; As[am][ak + 3] = a0.w;
        As[am][ak + 4] = a1.x; As[am][ak + 5] = a1.y; As[am][ak + 6] = a1.z; As[am][ak + 7] = a1.w;
        float4 b0 = *(const float4*)&W[(size_t)(c0 + bm) * K + k0 + bk];
        Bs[bm][bk + 0] = b0.x; Bs[bm][bk + 1] = b0.y; Bs[bm][bk + 2] = b0.z; Bs[bm][bk + 3] = b0.w;
        __syncthreads();
        #pragma unroll
        for (int kk = 0; kk < 16; ++kk) {
            float a[8], b[4];
            #pragma unroll
            for (int i = 0; i < 8; ++i) a[i] = As[ty * 8 + i][kk];
            #pragma unroll
            for (int j = 0; j < 4; ++j) b[j] = Bs[tx * 4 + j][kk];
            #pragma unroll
            for (int i = 0; i < 8; ++i)
                #pragma unroll
                for (int j = 0; j < 4; ++j) acc[i][j] += a[i] * b[j];
        }
        __syncthreads();
    }
    #pragma unroll
    for (int i = 0; i < 8; ++i) {
        int r = r0 + ty * 8 + i;
        #pragma unroll
        for (int j = 0; j < 4; ++j) {
            int c = c0 + tx * 4 + j;
            float val = acc[i][j] + bias[c];
            if (ACC) val += C[(size_t)r * NOut + c];
            C[(size_t)r * NOut + c] = val;
        }
    }
}

// ---------------------------------------------------------------- LayerNorm
__global__ __launch_bounds__(256) void ln_kernel(const float* __restrict__ h,
                                                 const float* __restrict__ gw,
                                                 const float* __restrict__ bw,
                                                 float* __restrict__ xn) {
    int lane = threadIdx.x & 63, wave = threadIdx.x >> 6;
    int node = blockIdx.x * 4 + wave;
    float4 v = ((const float4*)(h + (size_t)node * HID))[lane];
    float s = v.x + v.y + v.z + v.w;
    #pragma unroll
    for (int off = 32; off; off >>= 1) s += __shfl_xor(s, off, 64);
    float mu = s * (1.0f / HID);
    float dx = v.x - mu, dy = v.y - mu, dz = v.z - mu, dw = v.w - mu;
    float q = dx * dx + dy * dy + dz * dz + dw * dw;
    #pragma unroll
    for (int off = 32; off; off >>= 1) q += __shfl_xor(q, off, 64);
    float inv = rsqrtf(q * (1.0f / HID) + 1e-5f);
    int c = lane * 4;
    float4 o;
    o.x = dx * inv * gw[c + 0] + bw[c + 0];
    o.y = dy * inv * gw[c + 1] + bw[c + 1];
    o.z = dz * inv * gw[c + 2] + bw[c + 2];
    o.w = dw * inv * gw[c + 3] + bw[c + 3];
    ((float4*)(xn + (size_t)node * HID))[lane] = o;
}

// ---------------------------------------------------------------- fused edge attention
// one block per dst node; 256 threads = 256 channels; head = t/32.
__global__ __launch_bounds__(256) void agg_kernel(const float* __restrict__ q,
                                                  const float* __restrict__ k,
                                                  const float* __restrict__ v,
                                                  const int* __restrict__ indptr,
                                                  const int* __restrict__ ssrc,
                                                  float* __restrict__ outb) {
    const float scale = 0.17677669529663687f; // 1/sqrt(32)
    int n = blockIdx.x, t = threadIdx.x;
    float qv = q[(size_t)n * HID + t] * scale;
    int s0 = indptr[n], s1 = indptr[n + 1];
    float acc = 0.0f, ssum = 0.0f;
    for (int e = s0; e < s1; ++e) {
        int src = ssrc[e];
        float kv = k[(size_t)src * HID + t];
        float prod = qv * kv;
        #pragma unroll
        for (int off = 16; off; off >>= 1) prod += __shfl_xor(prod, off, 32);
        float p = __expf(prod);
        ssum += p;
        acc += p * v[(size_t)src * HID + t];
    }
    outb[(size_t)n * HID + t] = acc / fmaxf(ssum, 1e-16f);
}

// ---------------------------------------------------------------- beta gate + relu + residual
__global__ __launch_bounds__(256) void beta_kernel(const float* __restrict__ outb,
                                                   const float* __restrict__ skipb,
                                                   const float* __restrict__ wb,
                                                   float* __restrict__ h) {
    int lane = threadIdx.x & 63, wave = threadIdx.x >> 6;
    int node = blockIdx.x * 4 + wave;
    int c = lane * 4;
    float4 o  = ((const float4*)(outb  + (size_t)node * HID))[lane];
    float4 sk = ((const float4*)(skipb + (size_t)node * HID))[lane];
    float acc = o.x * wb[c + 0] + o.y * wb[c + 1] + o.z * wb[c + 2] + o.w * wb[c + 3]
              + sk.x * wb[HID + c + 0] + sk.y * wb[HID + c + 1]
              + sk.z * wb[HID + c + 2] + sk.w * wb[HID + c + 3]
              + (o.x - sk.x) * wb[2 * HID + c + 0] + (o.y - sk.y) * wb[2 * HID + c + 1]
              + (o.z - sk.z) * wb[2 * HID + c + 2] + (o.w - sk.w) * wb[2 * HID + c + 3];
    #pragma unroll
    for (int off = 32; off; off >>= 1) acc += __shfl_xor(acc, off, 64);
    float beta = 1.0f / (1.0f + __expf(-acc));
    float4 r = ((const float4*)(h + (size_t)node * HID))[lane];
    float4 out;
    out.x = fmaxf(beta * sk.x + (1.0f - beta) * o.x, 0.0f) + r.x;
    out.y = fmaxf(beta * sk.y + (1.0f - beta) * o.y, 0.0f) + r.y;
    out.z = fmaxf(beta * sk.z + (1.0f - beta) * o.z, 0.0f) + r.z;
    out.w = fmaxf(beta * sk.w + (1.0f - beta) * o.w, 0.0f) + r.w;
    ((float4*)(h + (size_t)node * HID))[lane] = out;
}

// ---------------------------------------------------------------- pooling + final MLP
__global__ __launch_bounds__(128) void bounds_kernel(const int* __restrict__ batch,
                                                     int* __restrict__ gstart) {
    int g = threadIdx.x;
    if (g > N_GRAPHS) return;
    int lo = 0, hi = N_NODES;
    while (lo < hi) { int mid = (lo + hi) >> 1; if (batch[mid] < g) lo = mid + 1; else hi = mid; }
    gstart[g] = lo;
}

__global__ __launch_bounds__(256) void pool_kernel(const float* __restrict__ h,
                                                   const int* __restrict__ gstart,
                                                   float* __restrict__ xg) {
    int g = blockIdx.x, t = threadIdx.x;
    int s = gstart[g], e = gstart[g + 1];
    float acc = 0.0f;
    for (int i = s; i < e; ++i) acc += h[(size_t)i * HID + t];
    float cnt = (float)(e - s);
    xg[(size_t)g * HID + t] = acc / fmaxf(cnt, 1.0f);
}

__global__ __launch_bounds__(256) void mlp_kernel(const float* __restrict__ xg,
                                                  const float* __restrict__ w1,
                                                  const float* __restrict__ b1,
                                                  const float* __restrict__ w2,
                                                  const float* __restrict__ b2,
                                                  float* __restrict__ out) {
    __shared__ float xr[256];
    __shared__ float red[256];
    int g = blockIdx.x, t = threadIdx.x;
    xr[t] = xg[(size_t)g * HID + t];
    __syncthreads();
    float s = b1[t];
    #pragma unroll 4
    for (int kk = 0; kk < 256; ++kk) s += xr[kk] * w1[t * 256 + kk];
    s = fmaxf(s, 0.0f);
    red[t] = s * w2[t];
    __syncthreads();
    for (int off = 128; off; off >>= 1) {
        if (t < off) red[t] += red[t + off];
        __syncthreads();
    }
    if (t == 0) out[g] = red[0] + b2[0];
}

// ---------------------------------------------------------------- host
extern "C" void kernel_launch(void* const* d_in, const int* in_sizes, int n_in,
                              void* d_out, int out_size, void* d_ws, size_t ws_size,
                              hipStream_t stream) {
    const float* x      = (const float*)d_in[0];
    const float* lpe    = (const float*)d_in[1];
    const float* pe_w1  = (const float*)d_in[2];
    const float* pe_b1  = (const float*)d_in[3];
    const float* pe_w2  = (const float*)d_in[4];
    const float* pe_b2  = (const float*)d_in[5];
    const float* emb_w  = (const float*)d_in[6];
    const float* emb_b  = (const float*)d_in[7];
    const float* ln_g   = (const float*)d_in[8];
    const float* ln_b   = (const float*)d_in[9];
    const float* wq     = (const float*)d_in[10];
    const float* bq     = (const float*)d_in[11];
    const float* wk     = (const float*)d_in[12];
    const float* bk     = (const float*)d_in[13];
    const float* wv     = (const float*)d_in[14];
    const float* bv     = (const float*)d_in[15];
    const float* wskip  = (const float*)d_in[16];
    const float* bskip  = (const float*)d_in[17];
    const float* wbeta  = (const float*)d_in[18];
    const float* mlp_w1 = (const float*)d_in[19];
    const float* mlp_b1 = (const float*)d_in[20];
    const float* mlp_w2 = (const float*)d_in[21];
    const float* mlp_b2 = (const float*)d_in[22];
    const int*   eidx   = (const int*)d_in[23];
    const int*   batch  = (const int*)d_in[24];

    const size_t NH = (size_t)N_NODES * HID;
    float* h     = (float*)d_ws;
    float* xn    = h + NH;
    float* qb    = xn + NH;
    float* kb    = qb + NH;
    float* vb    = kb + NH;
    float* skipb = vb + NH;
    float* outb  = skipb + NH;
    int* deg     = (int*)(outb + NH);
    int* indptr  = deg + N_NODES;
    int* cursor  = indptr + (N_NODES + 1);
    int* ssrc    = cursor + N_NODES;
    int* gstart  = ssrc + N_EDGES;
    float* xg    = (float*)(gstart + N_GRAPHS + 1 + 3); // pad to 16B

    // CSR by destination (edges static across layers)
    hipMemsetAsync(deg, 0, N_NODES * sizeof(int), stream);
    count_kernel<<<(N_EDGES + 255) / 256, 256, 0, stream>>>(eidx, deg);
    scan_kernel<<<1, 256, 0, stream>>>(deg, indptr, cursor);
    scatter_kernel<<<(N_EDGES + 255) / 256, 256, 0, stream>>>(eidx, cursor, ssrc);

    // h = x@emb_w^T + emb_b + pe_mlp(lpe)
    pe1_kernel<<<N_NODES, 256, 0, stream>>>(lpe, pe_w1, pe_b1, xn);
    gemm_kernel<false><<<dim3(250, 4), 256, 0, stream>>>(x, emb_w, emb_b, h, IN_CH, HID);
    gemm_kernel<true><<<dim3(250, 4), 256, 0, stream>>>(xn, pe_w2, pe_b2, h, HID, HID);

    for (int l = 0; l < N_LAYERS; ++l) {
        ln_kernel<<<N_NODES / 4, 256, 0, stream>>>(h, ln_g + l * HID, ln_b + l * HID, xn);
        gemm_kernel<false><<<dim3(250, 4), 256, 0, stream>>>(xn, wq + (size_t)l * HID * HID, bq + l * HID, qb, HID, HID);
        gemm_kernel<false><<<dim3(250, 4), 256, 0, stream>>>(xn, wk + (size_t)l * HID * HID, bk + l * HID, kb, HID, HID);
        gemm_kernel<false><<<dim3(250, 4), 256, 0, stream>>>(xn, wv + (size_t)l * HID * HID, bv + l * HID, vb, HID, HID);
        gemm_kernel<false><<<dim3(250, 4), 256, 0, stream>>>(xn, wskip + (size_t)l * HID * HID, bskip + l * HID, skipb, HID, HID);
        agg_kernel<<<N_NODES, 256, 0, stream>>>(qb, kb, vb, indptr, ssrc, outb);
        beta_kernel<<<N_NODES / 4, 256, 0, stream>>>(outb, skipb, wbeta + l * 3 * HID, h);
    }

    bounds_kernel<<<1, 128, 0, stream>>>(batch, gstart);
    pool_kernel<<<N_GRAPHS, 256, 0, stream>>>(h, gstart, xg);
    mlp_kernel<<<N_GRAPHS, 256, 0, stream>>>(xg, mlp_w1, mlp_b1, mlp_w2, mlp_b2, (float*)d_out);
}

// Round 2
// 1369.014 us; speedup vs baseline: 1.7846x; 1.7846x over previous
//
#include <hip/hip_runtime.h>

#define N_NODES   32000
#define N_EDGES   512000
#define IN_CH     128
#define HID       256
#define HEADS     8
#define D_HEAD    32
#define N_LAYERS  4
#define N_GRAPHS  64

typedef unsigned short u16;
typedef __bf16 bf16x8 __attribute__((ext_vector_type(8)));
typedef float f32x4 __attribute__((ext_vector_type(4)));
typedef unsigned short u16x8 __attribute__((ext_vector_type(8)));

__device__ __forceinline__ u16 f2bf(float x) {
    union { float f; unsigned int u; } v; v.f = x;
    unsigned int r = v.u + 0x7FFFu + ((v.u >> 16) & 1u);  // round-to-nearest-even
    return (u16)(r >> 16);
}
__device__ __forceinline__ float bf2f(u16 b) {
    union { unsigned int u; float f; } v; v.u = ((unsigned int)b) << 16;
    return v.f;
}

// ---------------------------------------------------------------- CSR build
__global__ __launch_bounds__(256) void count_kernel(const int* __restrict__ ei,
                                                    int* __restrict__ deg) {
    int e = blockIdx.x * 256 + threadIdx.x;
    if (e < N_EDGES) atomicAdd(&deg[ei[N_EDGES + e]], 1);
}

__global__ __launch_bounds__(256) void scan_kernel(const int* __restrict__ deg,
                                                   int* __restrict__ indptr,
                                                   int* __restrict__ cursor) {
    __shared__ int wsum[4];
    __shared__ int carry_s;
    __shared__ int total_s;
    int tid = threadIdx.x;
    int lane = tid & 63, wave = tid >> 6;
    if (tid == 0) carry_s = 0;
    __syncthreads();
    for (int base = 0; base < N_NODES; base += 256) {
        int i = base + tid;
        int v = (i < N_NODES) ? deg[i] : 0;
        int x = v;
        #pragma unroll
        for (int off = 1; off < 64; off <<= 1) {
            int t = __shfl_up(x, off, 64);
            if (lane >= off) x += t;
        }
        if (lane == 63) wsum[wave] = x;
        __syncthreads();
        if (tid == 0) {
            int s = 0;
            #pragma unroll
            for (int w = 0; w < 4; ++w) { int t = wsum[w]; wsum[w] = s; s += t; }
            total_s = s;
        }
        __syncthreads();
        int excl = carry_s + wsum[wave] + x - v;
        if (i < N_NODES) { indptr[i] = excl; cursor[i] = excl; }
        __syncthreads();
        if (tid == 0) carry_s += total_s;
        __syncthreads();
    }
    if (tid == 0) indptr[N_NODES] = carry_s;
}

__global__ __launch_bounds__(256) void scatter_kernel(const int* __restrict__ ei,
                                                      int* __restrict__ cursor,
                                                      int* __restrict__ ssrc) {
    int e = blockIdx.x * 256 + threadIdx.x;
    if (e < N_EDGES) {
        int dst = ei[N_EDGES + e];
        int pos = atomicAdd(&cursor[dst], 1);
        ssrc[pos] = ei[e];
    }
}

// ---------------------------------------------------------------- conversions
__global__ __launch_bounds__(256) void tob16_kernel(const float* __restrict__ src,
                                                    u16* __restrict__ dst, int n) {
    int i = blockIdx.x * 256 + threadIdx.x;
    if (i < n) dst[i] = f2bf(src[i]);
}

__global__ __launch_bounds__(256) void split_kernel(const float* __restrict__ src,
                                                    u16* __restrict__ hi,
                                                    u16* __restrict__ lo, int n) {
    int i = blockIdx.x * 256 + threadIdx.x;
    if (i >= n) return;
    float x = src[i];
    u16 h = f2bf(x);
    hi[i] = h;
    lo[i] = f2bf(x - bf2f(h));
}

// builds wcat[l][1024][256] = concat(wq,wk,wv,wskip) rows, split into hi/lo
__global__ __launch_bounds__(256) void wcat_kernel(const float* __restrict__ wq,
                                                   const float* __restrict__ wk,
                                                   const float* __restrict__ wv,
                                                   const float* __restrict__ ws,
                                                   u16* __restrict__ hi,
                                                   u16* __restrict__ lo) {
    int i = blockIdx.x * 256 + threadIdx.x;  // 4*1024*256 = 1048576 total
    int l = i >> 18;
    int rem = i & 262143;
    int r = rem >> 8, c = rem & 255;
    int seg = r >> 8, rr = r & 255;
    const float* w = seg == 0 ? wq : seg == 1 ? wk : seg == 2 ? wv : ws;
    float x = w[(size_t)l * 65536 + rr * 256 + c];
    u16 h = f2bf(x);
    hi[i] = h;
    lo[i] = f2bf(x - bf2f(h));
}

__global__ __launch_bounds__(256) void bcat_kernel(const float* __restrict__ bq,
                                                   const float* __restrict__ bk,
                                                   const float* __restrict__ bv,
                                                   const float* __restrict__ bs,
                                                   float* __restrict__ bcat) {
    int i = blockIdx.x * 256 + threadIdx.x;  // 4096
    int l = i >> 10, r = i & 1023;
    int seg = r >> 8, rr = r & 255;
    const float* b = seg == 0 ? bq : seg == 1 ? bk : seg == 2 ? bv : bs;
    bcat[i] = b[l * 256 + rr];
}

// ---------------------------------------------------------------- pe MLP stage 1
__global__ __launch_bounds__(256) void pe1_kernel(const float* __restrict__ lpe,
                                                  const float* __restrict__ w1,
                                                  const float* __restrict__ b1,
                                                  u16* __restrict__ t1b) {
    __shared__ float l[16];
    int n = blockIdx.x, j = threadIdx.x;
    if (j < 16) l[j] = lpe[n * 16 + j];
    __syncthreads();
    float s = b1[j];
    #pragma unroll
    for (int kk = 0; kk < 16; ++kk) s += l[kk] * w1[j * 16 + kk];
    t1b[(size_t)n * HID + j] = f2bf(fmaxf(s, 0.0f));
}

// ---------------------------------------------------------------- MFMA GEMM
// C[M x N] = A_bf16[M x K] @ (Whi + Wlo)[N x K]^T + bias, f32 accumulate.
// BM=BN=128, BK=64, 4 waves (2x2), each wave 64x64 (4x4 frags of 16x16x32).
// LDS chunk layout with XOR swizzle: elem_off(kc,r) = (kc*128 + (r&120) + ((r^kc)&7))*8
// MODE 0: C0[row*256+col] = val;  MODE 1: C0 += val;
// MODE 2 (QKVS, N=1024): col<256 -> qf (f32); 256..767 -> kvb (bf16); >=768 -> skipb (f32)
template <int MODE>
__global__ __launch_bounds__(256) void mgemm(const u16* __restrict__ A,
                                             const u16* __restrict__ Wh,
                                             const u16* __restrict__ Wl,
                                             const float* __restrict__ bias,
                                             int K,
                                             float* __restrict__ C0,
                                             float* __restrict__ qf,
                                             u16* __restrict__ kvb,
                                             float* __restrict__ skipb) {
    __shared__ __align__(16) u16 sA[128 * 64];
    __shared__ __align__(16) u16 sWh[128 * 64];
    __shared__ __align__(16) u16 sWl[128 * 64];
    const int tid = threadIdx.x;
    const int l = tid & 63, wid = tid >> 6;
    const int wm = wid >> 1, wn = wid & 1;
    const int lr = l & 15, lc = l >> 4;
    const int r0 = blockIdx.x * 128;
    const int c0 = blockIdx.y * 128;

    f32x4 acc[4][4];
    #pragma unroll
    for (int m = 0; m < 4; ++m)
        #pragma unroll
        for (int n = 0; n < 4; ++n) acc[m][n] = (f32x4){0.f, 0.f, 0.f, 0.f};

    const int kcS = tid & 7;          // staging: 16B chunk within row (128B/row group)
    for (int k0 = 0; k0 < K; k0 += 64) {
        #pragma unroll
        for (int j = 0; j < 4; ++j) {
            int r = (tid >> 3) + j * 32;
            int lo = (kcS * 128 + (r & 120) + ((r ^ kcS) & 7)) * 8;
            size_t gof = (size_t)(r0 + r) * K + k0 + kcS * 8;
            size_t gofw = (size_t)(c0 + r) * K + k0 + kcS * 8;
            *reinterpret_cast<u16x8*>(&sA[lo])  = *reinterpret_cast<const u16x8*>(&A[gof]);
            *reinterpret_cast<u16x8*>(&sWh[lo]) = *reinterpret_cast<const u16x8*>(&Wh[gofw]);
            *reinterpret_cast<u16x8*>(&sWl[lo]) = *reinterpret_cast<const u16x8*>(&Wl[gofw]);
        }
        __syncthreads();
        #pragma unroll
        for (int kk = 0; kk < 2; ++kk) {
            const int kc = kk * 4 + lc;
            bf16x8 a[4], wh[4], wl[4];
            #pragma unroll
            for (int m = 0; m < 4; ++m) {
                int r = wm * 64 + m * 16 + lr;
                a[m] = *reinterpret_cast<const bf16x8*>(
                    &sA[(kc * 128 + (r & 120) + ((r ^ kc) & 7)) * 8]);
            }
            #pragma unroll
            for (int n = 0; n < 4; ++n) {
                int r = wn * 64 + n * 16 + lr;
                int off = (kc * 128 + (r & 120) + ((r ^ kc) & 7)) * 8;
                wh[n] = *reinterpret_cast<const bf16x8*>(&sWh[off]);
                wl[n] = *reinterpret_cast<const bf16x8*>(&sWl[off]);
            }
            #pragma unroll
            for (int m = 0; m < 4; ++m)
                #pragma unroll
                for (int n = 0; n < 4; ++n) {
                    acc[m][n] = __builtin_amdgcn_mfma_f32_16x16x32_bf16(a[m], wh[n], acc[m][n], 0, 0, 0);
                    acc[m][n] = __builtin_amdgcn_mfma_f32_16x16x32_bf16(a[m], wl[n], acc[m][n], 0, 0, 0);
                }
        }
        __syncthreads();
    }

    #pragma unroll
    for (int n = 0; n < 4; ++n) {
        int col = c0 + wn * 64 + n * 16 + lr;
        float bv = bias[col];
        #pragma unroll
        for (int m = 0; m < 4; ++m) {
            int rowb = r0 + wm * 64 + m * 16 + lc * 4;
            #pragma unroll
            for (int i = 0; i < 4; ++i) {
                float val = acc[m][n][i] + bv;
                int row = rowb + i;
                if (MODE == 0) {
                    C0[(size_t)row * 256 + col] = val;
                } else if (MODE == 1) {
                    C0[(size_t)row * 256 + col] += val;
                } else {
                    if (c0 < 256)      qf[(size_t)row * 256 + col] = val;
                    else if (c0 < 768) kvb[(size_t)row * 512 + (col - 256)] = f2bf(val);
                    else               skipb[(size_t)row * 256 + (col - 768)] = val;
                }
            }
        }
    }
}

// ---------------------------------------------------------------- LayerNorm -> bf16
__global__ __launch_bounds__(256) void ln_kernel(const float* __restrict__ h,
                                                 const float* __restrict__ gw,
                                                 const float* __restrict__ bw,
                                                 u16* __restrict__ xnb) {
    int lane = threadIdx.x & 63, wave = threadIdx.x >> 6;
    int node = blockIdx.x * 4 + wave;
    float4 v = ((const float4*)(h + (size_t)node * HID))[lane];
    float s = v.x + v.y + v.z + v.w;
    #pragma unroll
    for (int off = 32; off; off >>= 1) s += __shfl_xor(s, off, 64);
    float mu = s * (1.0f / HID);
    float dx = v.x - mu, dy = v.y - mu, dz = v.z - mu, dw = v.w - mu;
    float q = dx * dx + dy * dy + dz * dz + dw * dw;
    #pragma unroll
    for (int off = 32; off; off >>= 1) q += __shfl_xor(q, off, 64);
    float inv = rsqrtf(q * (1.0f / HID) + 1e-5f);
    int c = lane * 4;
    float o0 = dx * inv * gw[c + 0] + bw[c + 0];
    float o1 = dy * inv * gw[c + 1] + bw[c + 1];
    float o2 = dz * inv * gw[c + 2] + bw[c + 2];
    float o3 = dw * inv * gw[c + 3] + bw[c + 3];
    uint2 pk;
    pk.x = (unsigned int)f2bf(o0) | ((unsigned int)f2bf(o1) << 16);
    pk.y = (unsigned int)f2bf(o2) | ((unsigned int)f2bf(o3) << 16);
    *reinterpret_cast<uint2*>(xnb + (size_t)node * HID + c) = pk;
}

// ---------------------------------------------------------------- fused edge attention
__global__ __launch_bounds__(256) void agg_kernel(const float* __restrict__ q,
                                                  const u16* __restrict__ kvb,
                                                  const int* __restrict__ indptr,
                                                  const int* __restrict__ ssrc,
                                                  float* __restrict__ outb) {
    const float scale = 0.17677669529663687f;  // 1/sqrt(32)
    int n = blockIdx.x, t = threadIdx.x;
    float qv = q[(size_t)n * HID + t] * scale;
    int s0 = indptr[n], s1 = indptr[n + 1];
    float acc = 0.0f, ssum = 0.0f;
    for (int e = s0; e < s1; ++e) {
        int src = ssrc[e];
        const u16* kvrow = kvb + (size_t)src * 512;
        float kv = bf2f(kvrow[t]);
        float prod = qv * kv;
        #pragma unroll
        for (int off = 16; off; off >>= 1) prod += __shfl_xor(prod, off, 32);
        float p = __expf(prod);
        ssum += p;
        acc += p * bf2f(kvrow[256 + t]);
    }
    outb[(size_t)n * HID + t] = acc / fmaxf(ssum, 1e-16f);
}

// ---------------------------------------------------------------- beta gate + relu + residual
__global__ __launch_bounds__(256) void beta_kernel(const float* __restrict__ outb,
                                                   const float* __restrict__ skipb,
                                                   const float* __restrict__ wb,
                                                   float* __restrict__ h) {
    int lane = threadIdx.x & 63, wave = threadIdx.x >> 6;
    int node = blockIdx.x * 4 + wave;
    int c = lane * 4;
    float4 o  = ((const float4*)(outb  + (size_t)node * HID))[lane];
    float4 sk = ((const float4*)(skipb + (size_t)node * HID))[lane];
    float acc = o.x * wb[c + 0] + o.y * wb[c + 1] + o.z * wb[c + 2] + o.w * wb[c + 3]
              + sk.x * wb[HID + c + 0] + sk.y * wb[HID + c + 1]
              + sk.z * wb[HID + c + 2] + sk.w * wb[HID + c + 3]
              + (o.x - sk.x) * wb[2 * HID + c + 0] + (o.y - sk.y) * wb[2 * HID + c + 1]
              + (o.z - sk.z) * wb[2 * HID + c + 2] + (o.w - sk.w) * wb[2 * HID + c + 3];
    #pragma unroll
    for (int off = 32; off; off >>= 1) acc += __shfl_xor(acc, off, 64);
    float beta = 1.0f / (1.0f + __expf(-acc));
    float4 r = ((const float4*)(h + (size_t)node * HID))[lane];
    float4 out;
    out.x = fmaxf(beta * sk.x + (1.0f - beta) * o.x, 0.0f) + r.x;
    out.y = fmaxf(beta * sk.y + (1.0f - beta) * o.y, 0.0f) + r.y;
    out.z = fmaxf(beta * sk.z + (1.0f - beta) * o.z, 0.0f) + r.z;
    out.w = fmaxf(beta * sk.w + (1.0f - beta) * o.w, 0.0f) + r.w;
    ((float4*)(h + (size_t)node * HID))[lane] = out;
}

// ---------------------------------------------------------------- pooling + final MLP
__global__ __launch_bounds__(128) void bounds_kernel(const int* __restrict__ batch,
                                                     int* __restrict__ gstart) {
    int g = threadIdx.x;
    if (g > N_GRAPHS) return;
    int lo = 0, hi = N_NODES;
    while (lo < hi) { int mid = (lo + hi) >> 1; if (batch[mid] < g) lo = mid + 1; else hi = mid; }
    gstart[g] = lo;
}

__global__ __launch_bounds__(256) void pool_kernel(const float* __restrict__ h,
                                                   const int* __restrict__ gstart,
                                                   float* __restrict__ xg) {
    int g = blockIdx.x, t = threadIdx.x;
    int s = gstart[g], e = gstart[g + 1];
    float acc = 0.0f;
    for (int i = s; i < e; ++i) acc += h[(size_t)i * HID + t];
    float cnt = (float)(e - s);
    xg[(size_t)g * HID + t] = acc / fmaxf(cnt, 1.0f);
}

__global__ __launch_bounds__(256) void mlp_kernel(const float* __restrict__ xg,
                                                  const float* __restrict__ w1,
                                                  const float* __restrict__ b1,
                                                  const float* __restrict__ w2,
                                                  const float* __restrict__ b2,
                                                  float* __restrict__ out) {
    __shared__ float xr[256];
    __shared__ float red[256];
    int g = blockIdx.x, t = threadIdx.x;
    xr[t] = xg[(size_t)g * HID + t];
    __syncthreads();
    float s = b1[t];
    #pragma unroll 4
    for (int kk = 0; kk < 256; ++kk) s += xr[kk] * w1[t * 256 + kk];
    s = fmaxf(s, 0.0f);
    red[t] = s * w2[t];
    __syncthreads();
    for (int off = 128; off; off >>= 1) {
        if (t < off) red[t] += red[t + off];
        __syncthreads();
    }
    if (t == 0) out[g] = red[0] + b2[0];
}

// ---------------------------------------------------------------- host
extern "C" void kernel_launch(void* const* d_in, const int* in_sizes, int n_in,
                              void* d_out, int out_size, void* d_ws, size_t ws_size,
                              hipStream_t stream) {
    const float* x      = (const float*)d_in[0];
    const float* lpe    = (const float*)d_in[1];
    const float* pe_w1  = (const float*)d_in[2];
    const float* pe_b1  = (const float*)d_in[3];
    const float* pe_w2  = (const float*)d_in[4];
    const float* pe_b2  = (const float*)d_in[5];
    const float* emb_w  = (const float*)d_in[6];
    const float* emb_b  = (const float*)d_in[7];
    const float* ln_g   = (const float*)d_in[8];
    const float* ln_b   = (const float*)d_in[9];
    const float* wq     = (const float*)d_in[10];
    const float* bq     = (const float*)d_in[11];
    const float* wk     = (const float*)d_in[12];
    const float* bk     = (const float*)d_in[13];
    const float* wv     = (const float*)d_in[14];
    const float* bv     = (const float*)d_in[15];
    const float* wskip  = (const float*)d_in[16];
    const float* bskip  = (const float*)d_in[17];
    const float* wbeta  = (const float*)d_in[18];
    const float* mlp_w1 = (const float*)d_in[19];
    const float* mlp_b1 = (const float*)d_in[20];
    const float* mlp_w2 = (const float*)d_in[21];
    const float* mlp_b2 = (const float*)d_in[22];
    const int*   eidx   = (const int*)d_in[23];
    const int*   batch  = (const int*)d_in[24];

    char* w = (char*)d_ws;
    const size_t NH = (size_t)N_NODES * HID;
    float* h     = (float*)w;           w += NH * 4;
    float* qf    = (float*)w;           w += NH * 4;
    float* skipb = (float*)w;           w += NH * 4;
    float* outb  = (float*)w;           w += NH * 4;
    float* xg    = (float*)w;           w += (size_t)N_GRAPHS * HID * 4;
    u16* xnb     = (u16*)w;             w += NH * 2;
    u16* kvb     = (u16*)w;             w += (size_t)N_NODES * 512 * 2;
    u16* xb      = (u16*)w;             w += (size_t)N_NODES * IN_CH * 2;
    u16* t1b     = (u16*)w;             w += NH * 2;
    u16* ehi     = (u16*)w;             w += 32768 * 2;
    u16* elo     = (u16*)w;             w += 32768 * 2;
    u16* p2hi    = (u16*)w;             w += 65536 * 2;
    u16* p2lo    = (u16*)w;             w += 65536 * 2;
    u16* wchi    = (u16*)w;             w += 1048576 * 2;
    u16* wclo    = (u16*)w;             w += 1048576 * 2;
    float* bcat  = (float*)w;           w += 4096 * 4;
    int* deg     = (int*)w;             w += N_NODES * 4;
    int* indptr  = (int*)w;             w += (N_NODES + 1) * 4;
    int* cursor  = (int*)w;             w += N_NODES * 4;
    int* ssrc    = (int*)w;             w += N_EDGES * 4;
    int* gstart  = (int*)w;             w += (N_GRAPHS + 1) * 4;

    // weight conversions (every call; deterministic)
    split_kernel<<<128, 256, 0, stream>>>(emb_w, ehi, elo, 32768);
    split_kernel<<<256, 256, 0, stream>>>(pe_w2, p2hi, p2lo, 65536);
    wcat_kernel<<<4096, 256, 0, stream>>>(wq, wk, wv, wskip, wchi, wclo);
    bcat_kernel<<<16, 256, 0, stream>>>(bq, bk, bv, bskip, bcat);
    tob16_kernel<<<16000, 256, 0, stream>>>(x, xb, N_NODES * IN_CH);

    // CSR by destination
    hipMemsetAsync(deg, 0, N_NODES * sizeof(int), stream);
    count_kernel<<<(N_EDGES + 255) / 256, 256, 0, stream>>>(eidx, deg);
    scan_kernel<<<1, 256, 0, stream>>>(deg, indptr, cursor);
    scatter_kernel<<<(N_EDGES + 255) / 256, 256, 0, stream>>>(eidx, cursor, ssrc);

    // h = x@emb_w^T + emb_b + pe_mlp(lpe)
    pe1_kernel<<<N_NODES, 256, 0, stream>>>(lpe, pe_w1, pe_b1, t1b);
    mgemm<0><<<dim3(250, 2), 256, 0, stream>>>(xb, ehi, elo, emb_b, IN_CH, h, nullptr, nullptr, nullptr);
    mgemm<1><<<dim3(250, 2), 256, 0, stream>>>(t1b, p2hi, p2lo, pe_b2, HID, h, nullptr, nullptr, nullptr);

    for (int l = 0; l < N_LAYERS; ++l) {
        ln_kernel<<<N_NODES / 4, 256, 0, stream>>>(h, ln_g + l * HID, ln_b + l * HID, xnb);
        mgemm<2><<<dim3(250, 8), 256, 0, stream>>>(xnb, wchi + (size_t)l * 262144,
                                                   wclo + (size_t)l * 262144,
                                                   bcat + l * 1024, HID,
                                                   nullptr, qf, kvb, skipb);
        agg_kernel<<<N_NODES, 256, 0, stream>>>(qf, kvb, indptr, ssrc, outb);
        beta_kernel<<<N_NODES / 4, 256, 0, stream>>>(outb, skipb, wbeta + l * 3 * HID, h);
    }

    bounds_kernel<<<1, 128, 0, stream>>>(batch, gstart);
    pool_kernel<<<N_GRAPHS, 256, 0, stream>>>(h, gstart, xg);
    mlp_kernel<<<N_GRAPHS, 256, 0, stream>>>(xg, mlp_w1, mlp_b1, mlp_w2, mlp_b2, (float*)d_out);
}

// Round 4
// 1279.758 us; speedup vs baseline: 1.9091x; 1.0697x over previous
//
#include <hip/hip_runtime.h>

#define N_NODES   32000
#define N_EDGES   512000
#define IN_CH     128
#define HID       256
#define HEADS     8
#define D_HEAD    32
#define N_LAYERS  4
#define N_GRAPHS  64

typedef unsigned short u16;
typedef __bf16 bf16x8 __attribute__((ext_vector_type(8)));
typedef float f32x4 __attribute__((ext_vector_type(4)));
typedef unsigned short u16x8 __attribute__((ext_vector_type(8)));

__device__ __forceinline__ u16 f2bf(float x) {
    union { float f; unsigned int u; } v; v.f = x;
    unsigned int r = v.u + 0x7FFFu + ((v.u >> 16) & 1u);  // round-to-nearest-even
    return (u16)(r >> 16);
}
__device__ __forceinline__ float bf2f(u16 b) {
    union { unsigned int u; float f; } v; v.u = ((unsigned int)b) << 16;
    return v.f;
}

// ---------------------------------------------------------------- CSR build
__global__ __launch_bounds__(256) void count_kernel(const int* __restrict__ ei,
                                                    int* __restrict__ deg) {
    int e = blockIdx.x * 256 + threadIdx.x;
    if (e < N_EDGES) atomicAdd(&deg[ei[N_EDGES + e]], 1);
}

__global__ __launch_bounds__(256) void scan_kernel(const int* __restrict__ deg,
                                                   int* __restrict__ indptr,
                                                   int* __restrict__ cursor) {
    __shared__ int wsum[4];
    __shared__ int carry_s;
    __shared__ int total_s;
    int tid = threadIdx.x;
    int lane = tid & 63, wave = tid >> 6;
    if (tid == 0) carry_s = 0;
    __syncthreads();
    for (int base = 0; base < N_NODES; base += 256) {
        int i = base + tid;
        int v = (i < N_NODES) ? deg[i] : 0;
        int x = v;
        #pragma unroll
        for (int off = 1; off < 64; off <<= 1) {
            int t = __shfl_up(x, off, 64);
            if (lane >= off) x += t;
        }
        if (lane == 63) wsum[wave] = x;
        __syncthreads();
        if (tid == 0) {
            int s = 0;
            #pragma unroll
            for (int w = 0; w < 4; ++w) { int t = wsum[w]; wsum[w] = s; s += t; }
            total_s = s;
        }
        __syncthreads();
        int excl = carry_s + wsum[wave] + x - v;
        if (i < N_NODES) { indptr[i] = excl; cursor[i] = excl; }
        __syncthreads();
        if (tid == 0) carry_s += total_s;
        __syncthreads();
    }
    if (tid == 0) indptr[N_NODES] = carry_s;
}

__global__ __launch_bounds__(256) void scatter_kernel(const int* __restrict__ ei,
                                                      int* __restrict__ cursor,
                                                      int* __restrict__ ssrc) {
    int e = blockIdx.x * 256 + threadIdx.x;
    if (e < N_EDGES) {
        int dst = ei[N_EDGES + e];
        int pos = atomicAdd(&cursor[dst], 1);
        ssrc[pos] = ei[e];
    }
}

// ---------------------------------------------------------------- conversions
__global__ __launch_bounds__(256) void tob16_kernel(const float* __restrict__ src,
                                                    u16* __restrict__ dst, int n) {
    int i = blockIdx.x * 256 + threadIdx.x;
    if (i < n) dst[i] = f2bf(src[i]);
}

__global__ __launch_bounds__(256) void split_kernel(const float* __restrict__ src,
                                                    u16* __restrict__ hi,
                                                    u16* __restrict__ lo, int n) {
    int i = blockIdx.x * 256 + threadIdx.x;
    if (i >= n) return;
    float x = src[i];
    u16 h = f2bf(x);
    hi[i] = h;
    lo[i] = f2bf(x - bf2f(h));
}

// builds wcat[l][1024][256] = concat(wq,wk,wv,wskip) rows, split into hi/lo
__global__ __launch_bounds__(256) void wcat_kernel(const float* __restrict__ wq,
                                                   const float* __restrict__ wk,
                                                   const float* __restrict__ wv,
                                                   const float* __restrict__ ws,
                                                   u16* __restrict__ hi,
                                                   u16* __restrict__ lo) {
    int i = blockIdx.x * 256 + threadIdx.x;  // 4*1024*256 = 1048576 total
    int l = i >> 18;
    int rem = i & 262143;
    int r = rem >> 8, c = rem & 255;
    int seg = r >> 8, rr = r & 255;
    const float* w = seg == 0 ? wq : seg == 1 ? wk : seg == 2 ? wv : ws;
    float x = w[(size_t)l * 65536 + rr * 256 + c];
    u16 h = f2bf(x);
    hi[i] = h;
    lo[i] = f2bf(x - bf2f(h));
}

__global__ __launch_bounds__(256) void bcat_kernel(const float* __restrict__ bq,
                                                   const float* __restrict__ bk,
                                                   const float* __restrict__ bv,
                                                   const float* __restrict__ bs,
                                                   float* __restrict__ bcat) {
    int i = blockIdx.x * 256 + threadIdx.x;  // 4096
    int l = i >> 10, r = i & 1023;
    int seg = r >> 8, rr = r & 255;
    const float* b = seg == 0 ? bq : seg == 1 ? bk : seg == 2 ? bv : bs;
    bcat[i] = b[l * 256 + rr];
}

// ---------------------------------------------------------------- pe MLP stage 1
__global__ __launch_bounds__(256) void pe1_kernel(const float* __restrict__ lpe,
                                                  const float* __restrict__ w1,
                                                  const float* __restrict__ b1,
                                                  u16* __restrict__ t1b) {
    __shared__ float l[16];
    int n = blockIdx.x, j = threadIdx.x;
    if (j < 16) l[j] = lpe[n * 16 + j];
    __syncthreads();
    float s = b1[j];
    #pragma unroll
    for (int kk = 0; kk < 16; ++kk) s += l[kk] * w1[j * 16 + kk];
    t1b[(size_t)n * HID + j] = f2bf(fmaxf(s, 0.0f));
}

// ---------------------------------------------------------------- MFMA GEMM
// C[M x N] = A_bf16[M x K] @ (Whi + Wlo)[N x K]^T + bias, f32 accumulate.
// BM=BN=128, BK=64, 4 waves (2x2), each wave 64x64 (4x4 frags of 16x16x32).
// MODE 0: C0[row*256+col] = val;  MODE 1: C0 += val;
// MODE 2 (QKVS, N=1024): col<256 -> qf (f32); 256..767 -> khv head-sliced bf16;
//                        >=768 -> skipb (f32)
template <int MODE>
__global__ __launch_bounds__(256) void mgemm(const u16* __restrict__ A,
                                             const u16* __restrict__ Wh,
                                             const u16* __restrict__ Wl,
                                             const float* __restrict__ bias,
                                             int K,
                                             float* __restrict__ C0,
                                             float* __restrict__ qf,
                                             u16* __restrict__ khv,
                                             float* __restrict__ skipb) {
    __shared__ __align__(16) u16 sA[128 * 64];
    __shared__ __align__(16) u16 sWh[128 * 64];
    __shared__ __align__(16) u16 sWl[128 * 64];
    const int tid = threadIdx.x;
    const int l = tid & 63, wid = tid >> 6;
    const int wm = wid >> 1, wn = wid & 1;
    const int lr = l & 15, lc = l >> 4;
    const int r0 = blockIdx.x * 128;
    const int c0 = blockIdx.y * 128;

    f32x4 acc[4][4];
    #pragma unroll
    for (int m = 0; m < 4; ++m)
        #pragma unroll
        for (int n = 0; n < 4; ++n) acc[m][n] = (f32x4){0.f, 0.f, 0.f, 0.f};

    const int kcS = tid & 7;          // staging: 16B chunk within row
    for (int k0 = 0; k0 < K; k0 += 64) {
        #pragma unroll
        for (int j = 0; j < 4; ++j) {
            int r = (tid >> 3) + j * 32;
            int lo = (kcS * 128 + (r & 120) + ((r ^ kcS) & 7)) * 8;
            size_t gof = (size_t)(r0 + r) * K + k0 + kcS * 8;
            size_t gofw = (size_t)(c0 + r) * K + k0 + kcS * 8;
            *reinterpret_cast<u16x8*>(&sA[lo])  = *reinterpret_cast<const u16x8*>(&A[gof]);
            *reinterpret_cast<u16x8*>(&sWh[lo]) = *reinterpret_cast<const u16x8*>(&Wh[gofw]);
            *reinterpret_cast<u16x8*>(&sWl[lo]) = *reinterpret_cast<const u16x8*>(&Wl[gofw]);
        }
        __syncthreads();
        #pragma unroll
        for (int kk = 0; kk < 2; ++kk) {
            const int kc = kk * 4 + lc;
            bf16x8 a[4], wh[4], wl[4];
            #pragma unroll
            for (int m = 0; m < 4; ++m) {
                int r = wm * 64 + m * 16 + lr;
                a[m] = *reinterpret_cast<const bf16x8*>(
                    &sA[(kc * 128 + (r & 120) + ((r ^ kc) & 7)) * 8]);
            }
            #pragma unroll
            for (int n = 0; n < 4; ++n) {
                int r = wn * 64 + n * 16 + lr;
                int off = (kc * 128 + (r & 120) + ((r ^ kc) & 7)) * 8;
                wh[n] = *reinterpret_cast<const bf16x8*>(&sWh[off]);
                wl[n] = *reinterpret_cast<const bf16x8*>(&sWl[off]);
            }
            #pragma unroll
            for (int m = 0; m < 4; ++m)
                #pragma unroll
                for (int n = 0; n < 4; ++n) {
                    acc[m][n] = __builtin_amdgcn_mfma_f32_16x16x32_bf16(a[m], wh[n], acc[m][n], 0, 0, 0);
                    acc[m][n] = __builtin_amdgcn_mfma_f32_16x16x32_bf16(a[m], wl[n], acc[m][n], 0, 0, 0);
                }
        }
        __syncthreads();
    }

    #pragma unroll
    for (int n = 0; n < 4; ++n) {
        int col = c0 + wn * 64 + n * 16 + lr;
        float bv = bias[col];
        #pragma unroll
        for (int m = 0; m < 4; ++m) {
            int rowb = r0 + wm * 64 + m * 16 + lc * 4;
            #pragma unroll
            for (int i = 0; i < 4; ++i) {
                float val = acc[m][n][i] + bv;
                int row = rowb + i;
                if (MODE == 0) {
                    C0[(size_t)row * 256 + col] = val;
                } else if (MODE == 1) {
                    C0[(size_t)row * 256 + col] += val;
                } else {
                    if (c0 < 256) {
                        qf[(size_t)row * 256 + col] = val;
                    } else if (c0 < 512) {
                        int cc = col - 256, hh = cc >> 5, ch = cc & 31;
                        khv[((size_t)hh * N_NODES + row) * 64 + ch] = f2bf(val);
                    } else if (c0 < 768) {
                        int cc = col - 512, hh = cc >> 5, ch = cc & 31;
                        khv[((size_t)hh * N_NODES + row) * 64 + 32 + ch] = f2bf(val);
                    } else {
                        skipb[(size_t)row * 256 + (col - 768)] = val;
                    }
                }
            }
        }
    }
}

// ---------------------------------------------------------------- LayerNorm -> bf16
__global__ __launch_bounds__(256) void ln_kernel(const float* __restrict__ h,
                                                 const float* __restrict__ gw,
                                                 const float* __restrict__ bw,
                                                 u16* __restrict__ xnb) {
    int lane = threadIdx.x & 63, wave = threadIdx.x >> 6;
    int node = blockIdx.x * 4 + wave;
    float4 v = ((const float4*)(h + (size_t)node * HID))[lane];
    float s = v.x + v.y + v.z + v.w;
    #pragma unroll
    for (int off = 32; off; off >>= 1) s += __shfl_xor(s, off, 64);
    float mu = s * (1.0f / HID);
    float dx = v.x - mu, dy = v.y - mu, dz = v.z - mu, dw = v.w - mu;
    float q = dx * dx + dy * dy + dz * dz + dw * dw;
    #pragma unroll
    for (int off = 32; off; off >>= 1) q += __shfl_xor(q, off, 64);
    float inv = rsqrtf(q * (1.0f / HID) + 1e-5f);
    int c = lane * 4;
    float o0 = dx * inv * gw[c + 0] + bw[c + 0];
    float o1 = dy * inv * gw[c + 1] + bw[c + 1];
    float o2 = dz * inv * gw[c + 2] + bw[c + 2];
    float o3 = dw * inv * gw[c + 3] + bw[c + 3];
    uint2 pk;
    pk.x = (unsigned int)f2bf(o0) | ((unsigned int)f2bf(o1) << 16);
    pk.y = (unsigned int)f2bf(o2) | ((unsigned int)f2bf(o3) << 16);
    *reinterpret_cast<uint2*>(xnb + (size_t)node * HID + c) = pk;
}

// ---------------------------------------------------------------- fused edge attention
// one wave per (node, head); head = blockIdx.x % 8 -> XCD affinity (per-head
// khv slice = 4MB = one XCD's L2). 8 edges per iteration, 8 lanes per edge:
// lanes j=0..3 load k (16B each), j=4..7 load v. 2-deep software pipeline.
__global__ __launch_bounds__(256) void agg_kernel(const float* __restrict__ q,
                                                  const u16* __restrict__ khv,
                                                  const int* __restrict__ indptr,
                                                  const int* __restrict__ ssrc,
                                                  float* __restrict__ outb) {
    const float scale = 0.17677669529663687f;  // 1/sqrt(32)
    const int lane = threadIdx.x & 63, wave = threadIdx.x >> 6;
    const int h = blockIdx.x & 7;
    const int n = (blockIdx.x >> 3) * 4 + wave;
    const int j = lane & 7, jj = lane >> 3;
    const bool is_k = j < 4;
    const int chof = (j & 3) * 8 + (is_k ? 0 : 32);

    float qv[8];
    if (is_k) {
        const float* qp = q + (size_t)n * HID + h * 32 + (j & 3) * 8;
        #pragma unroll
        for (int i = 0; i < 8; ++i) qv[i] = __builtin_nontemporal_load(qp + i) * scale;
    }

    const int s0 = indptr[n], s1 = indptr[n + 1];
    const u16* base = khv + (size_t)h * N_NODES * 64;
    float acc[8] = {0.f, 0.f, 0.f, 0.f, 0.f, 0.f, 0.f, 0.f};
    float ssum = 0.f;

    if (s0 < s1) {
        int ec = s0 + jj; if (ec > s1 - 1) ec = s1 - 1;
        int src = __builtin_nontemporal_load(&ssrc[ec]);
        u16x8 kv = *reinterpret_cast<const u16x8*>(base + (size_t)src * 64 + chof);
        for (int e0 = s0; e0 < s1; e0 += 8) {
            bool valid = (e0 + jj) < s1;
            bool more = (e0 + 8) < s1;
            u16x8 kvn = kv;
            if (more) {
                int en = e0 + 8 + jj; if (en > s1 - 1) en = s1 - 1;
                int srcn = __builtin_nontemporal_load(&ssrc[en]);
                kvn = *reinterpret_cast<const u16x8*>(base + (size_t)srcn * 64 + chof);
            }
            float prod = 0.f;
            if (is_k) {
                #pragma unroll
                for (int i = 0; i < 8; ++i) prod += qv[i] * bf2f(kv[i]);
            }
            prod += __shfl_xor(prod, 1, 64);
            prod += __shfl_xor(prod, 2, 64);
            float p = (is_k && valid) ? __expf(prod) : 0.f;
            ssum += p;
            float pv = __shfl_xor(p, 4, 64);
            if (!is_k) {
                #pragma unroll
                for (int i = 0; i < 8; ++i) acc[i] += pv * bf2f(kv[i]);
            }
            kv = kvn;
        }
    }

    // reduce over the 8 edge-groups (lane bits 3..5)
    #pragma unroll
    for (int d = 8; d <= 32; d <<= 1) {
        ssum += __shfl_xor(ssum, d, 64);
        #pragma unroll
        for (int i = 0; i < 8; ++i) acc[i] += __shfl_xor(acc[i], d, 64);
    }
    float sv = __shfl_xor(ssum, 4, 64);  // bring k-column ssum to v lanes
    if (!is_k && jj == 0) {
        float inv = 1.0f / fmaxf(sv, 1e-16f);
        float* op = outb + (size_t)n * HID + h * 32 + (j - 4) * 8;
        f32x4 o0 = {acc[0] * inv, acc[1] * inv, acc[2] * inv, acc[3] * inv};
        f32x4 o1 = {acc[4] * inv, acc[5] * inv, acc[6] * inv, acc[7] * inv};
        __builtin_nontemporal_store(o0, (f32x4*)op);
        __builtin_nontemporal_store(o1, (f32x4*)(op + 4));
    }
}

// ------------------------------------------- beta gate + relu + residual (+ next LN)
template <bool DO_LN>
__global__ __launch_bounds__(256) void beta_kernel(const float* __restrict__ outb,
                                                   const float* __restrict__ skipb,
                                                   const float* __restrict__ wb,
                                                   const float* __restrict__ gw,
                                                   const float* __restrict__ bw,
                                                   float* __restrict__ h,
                                                   u16* __restrict__ xnb) {
    int lane = threadIdx.x & 63, wave = threadIdx.x >> 6;
    int node = blockIdx.x * 4 + wave;
    int c = lane * 4;
    float4 o  = ((const float4*)(outb  + (size_t)node * HID))[lane];
    float4 sk = ((const float4*)(skipb + (size_t)node * HID))[lane];
    float acc = o.x * wb[c + 0] + o.y * wb[c + 1] + o.z * wb[c + 2] + o.w * wb[c + 3]
              + sk.x * wb[HID + c + 0] + sk.y * wb[HID + c + 1]
              + sk.z * wb[HID + c + 2] + sk.w * wb[HID + c + 3]
              + (o.x - sk.x) * wb[2 * HID + c + 0] + (o.y - sk.y) * wb[2 * HID + c + 1]
              + (o.z - sk.z) * wb[2 * HID + c + 2] + (o.w - sk.w) * wb[2 * HID + c + 3];
    #pragma unroll
    for (int off = 32; off; off >>= 1) acc += __shfl_xor(acc, off, 64);
    float beta = 1.0f / (1.0f + __expf(-acc));
    float4 r = ((const float4*)(h + (size_t)node * HID))[lane];
    float4 out;
    out.x = fmaxf(beta * sk.x + (1.0f - beta) * o.x, 0.0f) + r.x;
    out.y = fmaxf(beta * sk.y + (1.0f - beta) * o.y, 0.0f) + r.y;
    out.z = fmaxf(beta * sk.z + (1.0f - beta) * o.z, 0.0f) + r.z;
    out.w = fmaxf(beta * sk.w + (1.0f - beta) * o.w, 0.0f) + r.w;
    ((float4*)(h + (size_t)node * HID))[lane] = out;

    if (DO_LN) {
        float s = out.x + out.y + out.z + out.w;
        #pragma unroll
        for (int off = 32; off; off >>= 1) s += __shfl_xor(s, off, 64);
        float mu = s * (1.0f / HID);
        float dx = out.x - mu, dy = out.y - mu, dz = out.z - mu, dw = out.w - mu;
        float qq = dx * dx + dy * dy + dz * dz + dw * dw;
        #pragma unroll
        for (int off = 32; off; off >>= 1) qq += __shfl_xor(qq, off, 64);
        float inv = rsqrtf(qq * (1.0f / HID) + 1e-5f);
        float o0 = dx * inv * gw[c + 0] + bw[c + 0];
        float o1 = dy * inv * gw[c + 1] + bw[c + 1];
        float o2 = dz * inv * gw[c + 2] + bw[c + 2];
        float o3 = dw * inv * gw[c + 3] + bw[c + 3];
        uint2 pk;
        pk.x = (unsigned int)f2bf(o0) | ((unsigned int)f2bf(o1) << 16);
        pk.y = (unsigned int)f2bf(o2) | ((unsigned int)f2bf(o3) << 16);
        *reinterpret_cast<uint2*>(xnb + (size_t)node * HID + c) = pk;
    }
}

// ---------------------------------------------------------------- pooling + final MLP
__global__ __launch_bounds__(128) void bounds_kernel(const int* __restrict__ batch,
                                                     int* __restrict__ gstart) {
    int g = threadIdx.x;
    if (g > N_GRAPHS) return;
    int lo = 0, hi = N_NODES;
    while (lo < hi) { int mid = (lo + hi) >> 1; if (batch[mid] < g) lo = mid + 1; else hi = mid; }
    gstart[g] = lo;
}

__global__ __launch_bounds__(256) void pool_kernel(const float* __restrict__ h,
                                                   const int* __restrict__ gstart,
                                                   float* __restrict__ xg) {
    int g = blockIdx.x, t = threadIdx.x;
    int s = gstart[g], e = gstart[g + 1];
    float acc = 0.0f;
    for (int i = s; i < e; ++i) acc += h[(size_t)i * HID + t];
    float cnt = (float)(e - s);
    xg[(size_t)g * HID + t] = acc / fmaxf(cnt, 1.0f);
}

__global__ __launch_bounds__(256) void mlp_kernel(const float* __restrict__ xg,
                                                  const float* __restrict__ w1,
                                                  const float* __restrict__ b1,
                                                  const float* __restrict__ w2,
                                                  const float* __restrict__ b2,
                                                  float* __restrict__ out) {
    __shared__ float xr[256];
    __shared__ float red[256];
    int g = blockIdx.x, t = threadIdx.x;
    xr[t] = xg[(size_t)g * HID + t];
    __syncthreads();
    float s = b1[t];
    #pragma unroll 4
    for (int kk = 0; kk < 256; ++kk) s += xr[kk] * w1[t * 256 + kk];
    s = fmaxf(s, 0.0f);
    red[t] = s * w2[t];
    __syncthreads();
    for (int off = 128; off; off >>= 1) {
        if (t < off) red[t] += red[t + off];
        __syncthreads();
    }
    if (t == 0) out[g] = red[0] + b2[0];
}

// ---------------------------------------------------------------- host
extern "C" void kernel_launch(void* const* d_in, const int* in_sizes, int n_in,
                              void* d_out, int out_size, void* d_ws, size_t ws_size,
                              hipStream_t stream) {
    const float* x      = (const float*)d_in[0];
    const float* lpe    = (const float*)d_in[1];
    const float* pe_w1  = (const float*)d_in[2];
    const float* pe_b1  = (const float*)d_in[3];
    const float* pe_w2  = (const float*)d_in[4];
    const float* pe_b2  = (const float*)d_in[5];
    const float* emb_w  = (const float*)d_in[6];
    const float* emb_b  = (const float*)d_in[7];
    const float* ln_g   = (const float*)d_in[8];
    const float* ln_b   = (const float*)d_in[9];
    const float* wq     = (const float*)d_in[10];
    const float* bq     = (const float*)d_in[11];
    const float* wk     = (const float*)d_in[12];
    const float* bk     = (const float*)d_in[13];
    const float* wv     = (const float*)d_in[14];
    const float* bv     = (const float*)d_in[15];
    const float* wskip  = (const float*)d_in[16];
    const float* bskip  = (const float*)d_in[17];
    const float* wbeta  = (const float*)d_in[18];
    const float* mlp_w1 = (const float*)d_in[19];
    const float* mlp_b1 = (const float*)d_in[20];
    const float* mlp_w2 = (const float*)d_in[21];
    const float* mlp_b2 = (const float*)d_in[22];
    const int*   eidx   = (const int*)d_in[23];
    const int*   batch  = (const int*)d_in[24];

    char* w = (char*)d_ws;
    const size_t NH = (size_t)N_NODES * HID;
    float* h     = (float*)w;           w += NH * 4;
    float* qf    = (float*)w;           w += NH * 4;
    float* skipb = (float*)w;           w += NH * 4;
    float* outb  = (float*)w;           w += NH * 4;
    float* xg    = (float*)w;           w += (size_t)N_GRAPHS * HID * 4;
    u16* xnb     = (u16*)w;             w += NH * 2;
    u16* khv     = (u16*)w;             w += (size_t)HEADS * N_NODES * 64 * 2;
    u16* xb      = (u16*)w;             w += (size_t)N_NODES * IN_CH * 2;
    u16* t1b     = (u16*)w;             w += NH * 2;
    u16* ehi     = (u16*)w;             w += 32768 * 2;
    u16* elo     = (u16*)w;             w += 32768 * 2;
    u16* p2hi    = (u16*)w;             w += 65536 * 2;
    u16* p2lo    = (u16*)w;             w += 65536 * 2;
    u16* wchi    = (u16*)w;             w += 1048576 * 2;
    u16* wclo    = (u16*)w;             w += 1048576 * 2;
    float* bcat  = (float*)w;           w += 4096 * 4;
    int* deg     = (int*)w;             w += N_NODES * 4;
    int* indptr  = (int*)w;             w += (N_NODES + 1) * 4;
    int* cursor  = (int*)w;             w += N_NODES * 4;
    int* ssrc    = (int*)w;             w += N_EDGES * 4;
    int* gstart  = (int*)w;             w += (N_GRAPHS + 1) * 4;

    // weight conversions (every call; deterministic)
    split_kernel<<<128, 256, 0, stream>>>(emb_w, ehi, elo, 32768);
    split_kernel<<<256, 256, 0, stream>>>(pe_w2, p2hi, p2lo, 65536);
    wcat_kernel<<<4096, 256, 0, stream>>>(wq, wk, wv, wskip, wchi, wclo);
    bcat_kernel<<<16, 256, 0, stream>>>(bq, bk, bv, bskip, bcat);
    tob16_kernel<<<16000, 256, 0, stream>>>(x, xb, N_NODES * IN_CH);

    // CSR by destination
    hipMemsetAsync(deg, 0, N_NODES * sizeof(int), stream);
    count_kernel<<<(N_EDGES + 255) / 256, 256, 0, stream>>>(eidx, deg);
    scan_kernel<<<1, 256, 0, stream>>>(deg, indptr, cursor);
    scatter_kernel<<<(N_EDGES + 255) / 256, 256, 0, stream>>>(eidx, cursor, ssrc);

    // h = x@emb_w^T + emb_b + pe_mlp(lpe)
    pe1_kernel<<<N_NODES, 256, 0, stream>>>(lpe, pe_w1, pe_b1, t1b);
    mgemm<0><<<dim3(250, 2), 256, 0, stream>>>(xb, ehi, elo, emb_b, IN_CH, h, nullptr, nullptr, nullptr);
    mgemm<1><<<dim3(250, 2), 256, 0, stream>>>(t1b, p2hi, p2lo, pe_b2, HID, h, nullptr, nullptr, nullptr);

    ln_kernel<<<N_NODES / 4, 256, 0, stream>>>(h, ln_g, ln_b, xnb);
    for (int l = 0; l < N_LAYERS; ++l) {
        mgemm<2><<<dim3(250, 8), 256, 0, stream>>>(xnb, wchi + (size_t)l * 262144,
                                                   wclo + (size_t)l * 262144,
                                                   bcat + l * 1024, HID,
                                                   nullptr, qf, khv, skipb);
        agg_kernel<<<(N_NODES / 4) * 8, 256, 0, stream>>>(qf, khv, indptr, ssrc, outb);
        if (l < N_LAYERS - 1) {
            beta_kernel<true><<<N_NODES / 4, 256, 0, stream>>>(
                outb, skipb, wbeta + l * 3 * HID,
                ln_g + (l + 1) * HID, ln_b + (l + 1) * HID, h, xnb);
        } else {
            beta_kernel<false><<<N_NODES / 4, 256, 0, stream>>>(
                outb, skipb, wbeta + l * 3 * HID, nullptr, nullptr, h, nullptr);
        }
    }

    bounds_kernel<<<1, 128, 0, stream>>>(batch, gstart);
    pool_kernel<<<N_GRAPHS, 256, 0, stream>>>(h, gstart, xg);
    mlp_kernel<<<N_GRAPHS, 256, 0, stream>>>(xg, mlp_w1, mlp_b1, mlp_w2, mlp_b2, (float*)d_out);
}